// Round 1
// baseline (110778.625 us; speedup 1.0000x reference)
//
#include <hip/hip_runtime.h>
#include <stdint.h>

// Problem constants
#define NT   8192   // T
#define HID  1024   // H (= I)
#define NWG  128    // persistent workgroups in recurrence

// ---------- bf16 helpers (packed 2 x bf16 in a uint32: lo = elem0, hi = elem1) ----------
__device__ __forceinline__ float lo_f(uint32_t w) { return __uint_as_float(w << 16); }
__device__ __forceinline__ float hi_f(uint32_t w) { return __uint_as_float(w & 0xffff0000u); }
__device__ __forceinline__ uint32_t pack_bf16(float a, float b) {
    uint32_t ua = __float_as_uint(a), ub = __float_as_uint(b);
    ua = (ua + 0x7fffu + ((ua >> 16) & 1u)) >> 16;   // RNE
    ub = (ub + 0x7fffu + ((ub >> 16) & 1u)) >> 16;
    return (ua & 0xffffu) | (ub << 16);
}

// ---------- prep: combined bias ----------
__global__ void prep_bias(const float* __restrict__ a, const float* __restrict__ b,
                          float* __restrict__ o) {
    int i = blockIdx.x * 256 + threadIdx.x;
    if (i < 4096) o[i] = a[i] + b[i];
}

// ---------- prep: W_hh -> packed bf16, per-WG layout ----------
// Layout: wpk[w][lr][u], lr = wave*8 + gate*2 + jj  <->  row R = gate*1024 + w*8 + 2*wave + jj
// word u packs cols (2u, 2u+1)
__global__ void prep_whh(const float* __restrict__ Whh, uint32_t* __restrict__ wpk) {
    int idx = blockIdx.x * 256 + threadIdx.x;        // 0 .. 128*32*512-1
    int u    = idx & 511;
    int lr   = (idx >> 9) & 31;
    int w    = idx >> 14;
    int v    = lr >> 3;
    int gate = (lr >> 1) & 3;
    int jj   = lr & 1;
    int R = gate * 1024 + w * 8 + 2 * v + jj;
    const float* rp = Whh + (size_t)R * 1024 + 2 * u;
    wpk[idx] = pack_bf16(rp[0], rp[1]);
}

// ---------- fp32 tiled GEMM: out[M][N] = A[M][K] @ B[N][K]^T + bias[N] ----------
// 128x128 tile, BK=16, 256 threads, 8x8 microtile. PACK_OUT: write packed bf16 pairs.
template <bool PACK_OUT>
__launch_bounds__(256)
__global__ void gemm_bt(const float* __restrict__ A, const float* __restrict__ B,
                        const float* __restrict__ bias, void* __restrict__ outp,
                        int N, int K) {
    __shared__ float As[16 * 132];
    __shared__ float Bs[16 * 132];
    const int tid = threadIdx.x;
    const int bm = blockIdx.x, bn = blockIdx.y;
    const int tx = tid & 15, ty = tid >> 4;
    const int r = tid >> 2, cf = tid & 3;

    float acc[8][8];
#pragma unroll
    for (int i = 0; i < 8; ++i)
#pragma unroll
        for (int j = 0; j < 8; ++j) acc[i][j] = 0.f;

    const float* Ap = A + (size_t)(bm * 128 + r) * K + cf * 4;
    const float* Bp = B + (size_t)(bn * 128 + r) * K + cf * 4;

    for (int k0 = 0; k0 < K; k0 += 16) {
        float4 a0 = *(const float4*)(Ap + k0);
        float4 a1 = *(const float4*)(Ap + (size_t)64 * K + k0);
        float4 b0 = *(const float4*)(Bp + k0);
        float4 b1 = *(const float4*)(Bp + (size_t)64 * K + k0);
        __syncthreads();   // protect previous iteration's LDS reads
#pragma unroll
        for (int e = 0; e < 4; ++e) {
            As[(cf * 4 + e) * 132 + r]      = ((const float*)&a0)[e];
            As[(cf * 4 + e) * 132 + r + 64] = ((const float*)&a1)[e];
            Bs[(cf * 4 + e) * 132 + r]      = ((const float*)&b0)[e];
            Bs[(cf * 4 + e) * 132 + r + 64] = ((const float*)&b1)[e];
        }
        __syncthreads();
#pragma unroll
        for (int k = 0; k < 16; ++k) {
            const float4 av0 = *(const float4*)&As[k * 132 + ty * 8];
            const float4 av1 = *(const float4*)&As[k * 132 + ty * 8 + 4];
            const float4 bv0 = *(const float4*)&Bs[k * 132 + tx * 4];
            const float4 bv1 = *(const float4*)&Bs[k * 132 + tx * 4 + 64];
            const float a[8] = {av0.x, av0.y, av0.z, av0.w, av1.x, av1.y, av1.z, av1.w};
            const float b[8] = {bv0.x, bv0.y, bv0.z, bv0.w, bv1.x, bv1.y, bv1.z, bv1.w};
#pragma unroll
            for (int i = 0; i < 8; ++i)
#pragma unroll
                for (int j = 0; j < 8; ++j) acc[i][j] = fmaf(a[i], b[j], acc[i][j]);
        }
    }

    const int mb = bm * 128 + ty * 8;
    const int n0 = bn * 128 + tx * 4, n1 = n0 + 64;
    float bb[8];
#pragma unroll
    for (int j = 0; j < 4; ++j) { bb[j] = bias[n0 + j]; bb[4 + j] = bias[n1 + j]; }

    if (PACK_OUT) {
        uint32_t* o = (uint32_t*)outp;
        const int halfN = N >> 1;
#pragma unroll
        for (int i = 0; i < 8; ++i) {
            uint2 w0, w1;
            w0.x = pack_bf16(acc[i][0] + bb[0], acc[i][1] + bb[1]);
            w0.y = pack_bf16(acc[i][2] + bb[2], acc[i][3] + bb[3]);
            w1.x = pack_bf16(acc[i][4] + bb[4], acc[i][5] + bb[5]);
            w1.y = pack_bf16(acc[i][6] + bb[6], acc[i][7] + bb[7]);
            *(uint2*)(o + (size_t)(mb + i) * halfN + (n0 >> 1)) = w0;
            *(uint2*)(o + (size_t)(mb + i) * halfN + (n1 >> 1)) = w1;
        }
    } else {
        float* o = (float*)outp;
#pragma unroll
        for (int i = 0; i < 8; ++i) {
            float4 v0, v1;
            v0.x = acc[i][0] + bb[0]; v0.y = acc[i][1] + bb[1];
            v0.z = acc[i][2] + bb[2]; v0.w = acc[i][3] + bb[3];
            v1.x = acc[i][4] + bb[4]; v1.y = acc[i][5] + bb[5];
            v1.z = acc[i][6] + bb[6]; v1.w = acc[i][7] + bb[7];
            *(float4*)(o + (size_t)(mb + i) * N + n0) = v0;
            *(float4*)(o + (size_t)(mb + i) * N + n1) = v1;
        }
    }
}

// ---------- persistent LSTM recurrence ----------
// 128 WGs x 256 threads. WG w owns hidden units j = w*8 .. w*8+7.
// Wave v owns j = w*8 + 2v, w*8 + 2v + 1 (all 4 gates), rows in LDS at lr = v*8 + gate*2 + jj.
__launch_bounds__(256)
__global__ void lstm_rec(const uint32_t* __restrict__ wpk, const uint32_t* __restrict__ pxp,
                         volatile uint32_t* h_packed, float* __restrict__ lstm_out,
                         uint32_t* bar) {
    extern __shared__ uint32_t Wl[];   // 32*512 words = 64 KB
    const int tid = threadIdx.x, w = blockIdx.x;

    {   // stage weight slice (coalesced uint4)
        const uint4* src = (const uint4*)(wpk + (size_t)w * 16384);
        uint4* dst = (uint4*)Wl;
        for (int i = tid; i < 4096; i += 256) dst[i] = src[i];
    }
    __syncthreads();

    const int wave = tid >> 6, L = tid & 63;
    float c0 = 0.f;                    // cell state, live only in lanes 0,1 of each wave
    uint32_t* grp  = bar;              // 8 counters, stride 32 uints (128B apart)
    uint32_t* root = bar + 256;
    uint32_t* gen  = bar + 288;

    for (int t = 0; t < NT; ++t) {
        // h_{t-1}, packed bf16 (512 words), L1-bypassing loads
        uint32_t hp[8];
#pragma unroll
        for (int m = 0; m < 8; ++m) hp[m] = h_packed[L + 64 * m];

        // px for my gates (issued early, latency hidden under the dot products)
        float pxv[4] = {0.f, 0.f, 0.f, 0.f};
        if (L < 2) {
#pragma unroll
            for (int g = 0; g < 4; ++g) {
                int R = g * 1024 + w * 8 + 2 * wave + L;
                uint32_t pw = pxp[(size_t)t * 2048 + (R >> 1)];
                pxv[g] = (R & 1) ? hi_f(pw) : lo_f(pw);
            }
        }

        float hf[16];
#pragma unroll
        for (int m = 0; m < 8; ++m) { hf[2 * m] = lo_f(hp[m]); hf[2 * m + 1] = hi_f(hp[m]); }

        // 8 row-dots: row rr = gate*2 + jj, lane handles cols 2(L+64m), 2(L+64m)+1
        float acc[8];
        const uint32_t* base = Wl + (wave * 8) * 512 + L;
#pragma unroll
        for (int rr = 0; rr < 8; ++rr) {
            const uint32_t* rp = base + rr * 512;
            float a = 0.f;
#pragma unroll
            for (int m = 0; m < 8; ++m) {
                uint32_t wv = rp[64 * m];
                a = fmaf(lo_f(wv), hf[2 * m], a);
                a = fmaf(hi_f(wv), hf[2 * m + 1], a);
            }
            acc[rr] = a;
        }
        // wave-wide butterfly reduction
#pragma unroll
        for (int rr = 0; rr < 8; ++rr) {
#pragma unroll
            for (int off = 32; off; off >>= 1) acc[rr] += __shfl_xor(acc[rr], off, 64);
        }

        // elementwise gate update: lanes 0,1 of each wave (jj = L)
        if (L < 2) {
            float gi = acc[0 + L] + pxv[0];
            float gf = acc[2 + L] + pxv[1];
            float gg = acc[4 + L] + pxv[2];
            float go = acc[6 + L] + pxv[3];
            float iv = 1.f / (1.f + __expf(-gi));
            float fv = 1.f / (1.f + __expf(-gf));
            float gv = tanhf(gg);
            float ov = 1.f / (1.f + __expf(-go));
            c0 = fv * c0 + iv * gv;
            float h = ov * tanhf(c0);
            int j = w * 8 + 2 * wave + L;
            lstm_out[(size_t)t * 1024 + j] = h;
            float hn = __shfl(h, 1, 64);          // lane 1 is active here
            if (L == 0) h_packed[4 * w + wave] = pack_bf16(h, hn);
        }

        // grid barrier: 2-level arrival (8 groups of 16) + generation flag, agent scope
        __syncthreads();   // drains vmcnt: all h stores are in L2 before release
        if (tid == 0) {
            const uint32_t tgt = (uint32_t)(t + 1);
            uint32_t old = __hip_atomic_fetch_add(&grp[(w & 7) * 32], 1u,
                                                  __ATOMIC_ACQ_REL, __HIP_MEMORY_SCOPE_AGENT);
            if (old == tgt * 16u - 1u) {
                uint32_t oldr = __hip_atomic_fetch_add(root, 1u,
                                                       __ATOMIC_ACQ_REL, __HIP_MEMORY_SCOPE_AGENT);
                if (oldr == tgt * 8u - 1u)
                    __hip_atomic_store(gen, tgt, __ATOMIC_RELEASE, __HIP_MEMORY_SCOPE_AGENT);
            }
            while (__hip_atomic_load(gen, __ATOMIC_ACQUIRE, __HIP_MEMORY_SCOPE_AGENT) < tgt) {}
        }
        __syncthreads();
    }
}

// ---------- log-softmax over axis 0 (columns of [8192][512]) ----------
__global__ void sm_partial(const float* __restrict__ logits, float* __restrict__ pM,
                           float* __restrict__ pS) {
    const int cb = blockIdx.x, rb = blockIdx.y, tid = threadIdx.x;
    const int c = cb * 64 + (tid & 63);
    const int r0 = rb * 256 + (tid >> 6) * 64;
    const float* p = logits + (size_t)r0 * 512 + c;
    float m = -1e30f;
    for (int k = 0; k < 64; ++k) m = fmaxf(m, p[(size_t)k * 512]);
    float s = 0.f;
    for (int k = 0; k < 64; ++k) s += __expf(p[(size_t)k * 512] - m);
    __shared__ float sM[4][64], sS[4][64];
    sM[tid >> 6][tid & 63] = m;
    sS[tid >> 6][tid & 63] = s;
    __syncthreads();
    if (tid < 64) {
        float M = sM[0][tid];
        for (int i = 1; i < 4; ++i) M = fmaxf(M, sM[i][tid]);
        float S = 0.f;
        for (int i = 0; i < 4; ++i) S += sS[i][tid] * __expf(sM[i][tid] - M);
        pM[rb * 512 + cb * 64 + tid] = M;
        pS[rb * 512 + cb * 64 + tid] = S;
    }
}

__global__ void sm_combine(const float* __restrict__ pM, const float* __restrict__ pS,
                           float* __restrict__ cc) {
    const int c = threadIdx.x;   // 512 threads
    float M = -1e30f;
    for (int i = 0; i < 32; ++i) M = fmaxf(M, pM[i * 512 + c]);
    float S = 0.f;
    for (int i = 0; i < 32; ++i) S += pS[i * 512 + c] * __expf(pM[i * 512 + c] - M);
    cc[c] = M + logf(S);
}

__global__ void sm_apply(float* __restrict__ out, const float* __restrict__ cc) {
    const int idx = blockIdx.x * 256 + threadIdx.x;    // float4 index, exactly 1M
    float4 v = ((const float4*)out)[idx];
    float4 b = ((const float4*)cc)[idx & 127];
    v.x -= b.x; v.y -= b.y; v.z -= b.z; v.w -= b.w;
    ((float4*)out)[idx] = v;
}

// ---------- launch ----------
extern "C" void kernel_launch(void* const* d_in, const int* in_sizes, int n_in,
                              void* d_out, int out_size, void* d_ws, size_t ws_size,
                              hipStream_t stream) {
    (void)in_sizes; (void)n_in; (void)out_size; (void)ws_size;
    const float* x    = (const float*)d_in[0];
    const float* Wih  = (const float*)d_in[1];
    const float* Whh  = (const float*)d_in[2];
    const float* bih  = (const float*)d_in[3];
    const float* bhh  = (const float*)d_in[4];
    const float* Wout = (const float*)d_in[5];
    const float* bout = (const float*)d_in[6];
    float* out = (float*)d_out;

    char* ws = (char*)d_ws;
    uint32_t* pxp   = (uint32_t*)(ws + 0ull);            // 8192*2048 words   (67,108,864 B)
    uint32_t* wpk   = (uint32_t*)(ws + 67108864ull);     // 128*32*512 words  ( 8,388,608 B)
    float* lstm_out = (float*)   (ws + 75497472ull);     // 8192*1024 f32     (33,554,432 B)
    float* biasc    = (float*)   (ws + 109051904ull);    // 4096 f32
    uint32_t* hpk   = (uint32_t*)(ws + 109068288ull);    // 512 words
    uint32_t* bar   = (uint32_t*)(ws + 109070336ull);    // 1024 words
    float* pM       = (float*)   (ws + 109074432ull);    // 32*512 f32
    float* pS       = (float*)   (ws + 109139968ull);    // 32*512 f32
    float* cc       = (float*)   (ws + 109205504ull);    // 512 f32

    // deterministic per-call state
    hipMemsetAsync(hpk, 0, 2048, stream);
    hipMemsetAsync(bar, 0, 4096, stream);

    prep_whh<<<8192, 256, 0, stream>>>(Whh, wpk);
    prep_bias<<<16, 256, 0, stream>>>(bih, bhh, biasc);

    // px = x @ W_ih^T + (b_ih + b_hh), stored packed bf16
    gemm_bt<true><<<dim3(64, 32), 256, 0, stream>>>(x, Wih, biasc, (void*)pxp, 4096, 1024);

    hipFuncSetAttribute(reinterpret_cast<const void*>(&lstm_rec),
                        hipFuncAttributeMaxDynamicSharedMemorySize, 65536);
    lstm_rec<<<NWG, 256, 65536, stream>>>(wpk, pxp, hpk, lstm_out, bar);

    // logits = lstm_out @ W_out^T + b_out  -> d_out
    gemm_bt<false><<<dim3(64, 4), 256, 0, stream>>>(lstm_out, Wout, bout, (void*)out, 512, 1024);

    // log-softmax over sequence axis (columns)
    sm_partial<<<dim3(8, 32), 256, 0, stream>>>(out, pM, pS);
    sm_combine<<<1, 512, 0, stream>>>(pM, pS, cc);
    sm_apply<<<4096, 256, 0, stream>>>(out, cc);
}

// Round 2
// 28700.891 us; speedup vs baseline: 3.8598x; 3.8598x over previous
//
#include <hip/hip_runtime.h>
#include <stdint.h>

// Problem constants
#define NT   8192   // T
#define HID  1024   // H (= I)
#define NWG  128    // persistent workgroups in recurrence

// ---------- bf16 helpers (packed 2 x bf16 in a uint32: lo = elem0, hi = elem1) ----------
__device__ __forceinline__ float lo_f(uint32_t w) { return __uint_as_float(w << 16); }
__device__ __forceinline__ float hi_f(uint32_t w) { return __uint_as_float(w & 0xffff0000u); }
__device__ __forceinline__ uint32_t bf16_bits(float a) {
    uint32_t ua = __float_as_uint(a);
    ua = (ua + 0x7fffu + ((ua >> 16) & 1u)) >> 16;   // RNE
    return ua & 0xffffu;
}
__device__ __forceinline__ uint32_t pack_bf16(float a, float b) {
    return bf16_bits(a) | (bf16_bits(b) << 16);
}
__device__ __forceinline__ float fast_rcp(float x) { return __builtin_amdgcn_rcpf(x); }
__device__ __forceinline__ float fast_sig(float x) { return fast_rcp(1.f + __expf(-x)); }
__device__ __forceinline__ float fast_tanh(float x) {
    return 1.f - 2.f * fast_rcp(1.f + __expf(2.f * x));
}

// ---------- prep: combined bias ----------
__global__ void prep_bias(const float* __restrict__ a, const float* __restrict__ b,
                          float* __restrict__ o) {
    int i = blockIdx.x * 256 + threadIdx.x;
    if (i < 4096) o[i] = a[i] + b[i];
}

// ---------- prep: W_hh -> packed bf16, per-WG layout ----------
// Layout: wpk[w][lr][u], lr = wave*8 + gate*2 + jj  <->  row R = gate*1024 + w*8 + 2*wave + jj
// word u packs cols (2u, 2u+1)
__global__ void prep_whh(const float* __restrict__ Whh, uint32_t* __restrict__ wpk) {
    int idx = blockIdx.x * 256 + threadIdx.x;        // 0 .. 128*32*512-1
    int u    = idx & 511;
    int lr   = (idx >> 9) & 31;
    int w    = idx >> 14;
    int v    = lr >> 3;
    int gate = (lr >> 1) & 3;
    int jj   = lr & 1;
    int R = gate * 1024 + w * 8 + 2 * v + jj;
    const float* rp = Whh + (size_t)R * 1024 + 2 * u;
    wpk[idx] = pack_bf16(rp[0], rp[1]);
}

// ---------- fp32 tiled GEMM: out[M][N] = A[M][K] @ B[N][K]^T + bias[N] ----------
// 128x128 tile, BK=16, 256 threads, 8x8 microtile. PACK_OUT: write packed bf16 pairs.
template <bool PACK_OUT>
__launch_bounds__(256)
__global__ void gemm_bt(const float* __restrict__ A, const float* __restrict__ B,
                        const float* __restrict__ bias, void* __restrict__ outp,
                        int N, int K) {
    __shared__ float As[16 * 132];
    __shared__ float Bs[16 * 132];
    const int tid = threadIdx.x;
    const int bm = blockIdx.x, bn = blockIdx.y;
    const int tx = tid & 15, ty = tid >> 4;
    const int r = tid >> 2, cf = tid & 3;

    float acc[8][8];
#pragma unroll
    for (int i = 0; i < 8; ++i)
#pragma unroll
        for (int j = 0; j < 8; ++j) acc[i][j] = 0.f;

    const float* Ap = A + (size_t)(bm * 128 + r) * K + cf * 4;
    const float* Bp = B + (size_t)(bn * 128 + r) * K + cf * 4;

    for (int k0 = 0; k0 < K; k0 += 16) {
        float4 a0 = *(const float4*)(Ap + k0);
        float4 a1 = *(const float4*)(Ap + (size_t)64 * K + k0);
        float4 b0 = *(const float4*)(Bp + k0);
        float4 b1 = *(const float4*)(Bp + (size_t)64 * K + k0);
        __syncthreads();   // protect previous iteration's LDS reads
#pragma unroll
        for (int e = 0; e < 4; ++e) {
            As[(cf * 4 + e) * 132 + r]      = ((const float*)&a0)[e];
            As[(cf * 4 + e) * 132 + r + 64] = ((const float*)&a1)[e];
            Bs[(cf * 4 + e) * 132 + r]      = ((const float*)&b0)[e];
            Bs[(cf * 4 + e) * 132 + r + 64] = ((const float*)&b1)[e];
        }
        __syncthreads();
#pragma unroll
        for (int k = 0; k < 16; ++k) {
            const float4 av0 = *(const float4*)&As[k * 132 + ty * 8];
            const float4 av1 = *(const float4*)&As[k * 132 + ty * 8 + 4];
            const float4 bv0 = *(const float4*)&Bs[k * 132 + tx * 4];
            const float4 bv1 = *(const float4*)&Bs[k * 132 + tx * 4 + 64];
            const float a[8] = {av0.x, av0.y, av0.z, av0.w, av1.x, av1.y, av1.z, av1.w};
            const float b[8] = {bv0.x, bv0.y, bv0.z, bv0.w, bv1.x, bv1.y, bv1.z, bv1.w};
#pragma unroll
            for (int i = 0; i < 8; ++i)
#pragma unroll
                for (int j = 0; j < 8; ++j) acc[i][j] = fmaf(a[i], b[j], acc[i][j]);
        }
    }

    const int mb = bm * 128 + ty * 8;
    const int n0 = bn * 128 + tx * 4, n1 = n0 + 64;
    float bb[8];
#pragma unroll
    for (int j = 0; j < 4; ++j) { bb[j] = bias[n0 + j]; bb[4 + j] = bias[n1 + j]; }

    if (PACK_OUT) {
        uint32_t* o = (uint32_t*)outp;
        const int halfN = N >> 1;
#pragma unroll
        for (int i = 0; i < 8; ++i) {
            uint2 w0, w1;
            w0.x = pack_bf16(acc[i][0] + bb[0], acc[i][1] + bb[1]);
            w0.y = pack_bf16(acc[i][2] + bb[2], acc[i][3] + bb[3]);
            w1.x = pack_bf16(acc[i][4] + bb[4], acc[i][5] + bb[5]);
            w1.y = pack_bf16(acc[i][6] + bb[6], acc[i][7] + bb[7]);
            *(uint2*)(o + (size_t)(mb + i) * halfN + (n0 >> 1)) = w0;
            *(uint2*)(o + (size_t)(mb + i) * halfN + (n1 >> 1)) = w1;
        }
    } else {
        float* o = (float*)outp;
#pragma unroll
        for (int i = 0; i < 8; ++i) {
            float4 v0, v1;
            v0.x = acc[i][0] + bb[0]; v0.y = acc[i][1] + bb[1];
            v0.z = acc[i][2] + bb[2]; v0.w = acc[i][3] + bb[3];
            v1.x = acc[i][4] + bb[4]; v1.y = acc[i][5] + bb[5];
            v1.z = acc[i][6] + bb[6]; v1.w = acc[i][7] + bb[7];
            *(float4*)(o + (size_t)(mb + i) * N + n0) = v0;
            *(float4*)(o + (size_t)(mb + i) * N + n1) = v1;
        }
    }
}

// ---------- persistent LSTM recurrence, barrier-free tagged dataflow ----------
// h word j = (tag<<16) | bf16(h_j). H[s] lives in buf[s&1], tagged s. H[0]=tag 0=memset 0.
// Writer of H[s] observed all tags s-1 => every wave finished reading H[s-2] => safe to
// overwrite buf[s&1] (which held H[s-2]). No barriers, no fences, no intra-WG sync in loop.
// 128 WGs x 256 threads; WG w owns units 8w..8w+7; wave v owns units 8w+2v, 8w+2v+1.
__launch_bounds__(256)
__global__ void lstm_rec(const uint32_t* __restrict__ wpk, const uint32_t* __restrict__ pxp,
                         uint32_t* htag, float* __restrict__ lstm_out) {
    extern __shared__ uint32_t Wl[];   // 32*512 words = 64 KB
    const int tid = threadIdx.x, w = blockIdx.x;

    {   // stage weight slice (coalesced uint4)
        const uint4* src = (const uint4*)(wpk + (size_t)w * 16384);
        uint4* dst = (uint4*)Wl;
        for (int i = tid; i < 4096; i += 256) dst[i] = src[i];
    }
    __syncthreads();

    const int wave = tid >> 6, L = tid & 63;
    float c0 = 0.f;                    // cell state, live only in lanes 0,1 of each wave
    uint64_t* buf0 = (uint64_t*)htag;          // 512 u64 = words 0..1023   (H[even])
    uint64_t* buf1 = (uint64_t*)(htag + 1024); //                           (H[odd])
    const uint32_t* base = Wl + (wave * 8) * 512 + L;

    for (int t = 0; t < NT; ++t) {
        const uint32_t tg = (uint32_t)t;            // tag of H[t]
        uint64_t* srcb = (t & 1) ? buf1 : buf0;     // H[t]
        uint32_t* dstb = (uint32_t*)((t & 1) ? buf0 : buf1);  // H[t+1]

        // px for my gates — plain cached loads, issued before the poll so the
        // latency hides under it
        float pxv[4] = {0.f, 0.f, 0.f, 0.f};
        if (L < 2) {
#pragma unroll
            for (int g = 0; g < 4; ++g) {
                int R = g * 1024 + w * 8 + 2 * wave + L;
                uint32_t pw = pxp[(size_t)t * 2048 + (R >> 1)];
                pxv[g] = (R & 1) ? hi_f(pw) : lo_f(pw);
            }
        }

        // poll all 1024 tagged h words (each lane: 8 x u64 = pairs (2(L+64m), +1))
        uint64_t hp[8];
        int tries = 0;
        for (;;) {
            int ok = 1;
#pragma unroll
            for (int m = 0; m < 8; ++m)
                hp[m] = __hip_atomic_load(srcb + (L + 64 * m),
                                          __ATOMIC_RELAXED, __HIP_MEMORY_SCOPE_AGENT);
#pragma unroll
            for (int m = 0; m < 8; ++m) {
                uint32_t lo = (uint32_t)hp[m], hi = (uint32_t)(hp[m] >> 32);
                ok &= ((lo >> 16) == tg) & ((hi >> 16) == tg);
            }
            if (__all(ok)) break;
            if (++tries > (1 << 15)) break;   // tripwire: hang -> visible absmax failure
        }

        float hf[16];
#pragma unroll
        for (int m = 0; m < 8; ++m) {
            hf[2 * m]     = __uint_as_float(((uint32_t)hp[m]) << 16);
            hf[2 * m + 1] = __uint_as_float(((uint32_t)(hp[m] >> 32)) << 16);
        }

        // 8 row-dots: row rr = gate*2 + jj, lane handles cols 2(L+64m), 2(L+64m)+1
        float acc[8];
#pragma unroll
        for (int rr = 0; rr < 8; ++rr) {
            const uint32_t* rp = base + rr * 512;
            float a = 0.f;
#pragma unroll
            for (int m = 0; m < 8; ++m) {
                uint32_t wv = rp[64 * m];
                a = fmaf(lo_f(wv), hf[2 * m], a);
                a = fmaf(hi_f(wv), hf[2 * m + 1], a);
            }
            acc[rr] = a;
        }
        // wave-wide butterfly reduction
#pragma unroll
        for (int rr = 0; rr < 8; ++rr) {
#pragma unroll
            for (int off = 32; off; off >>= 1) acc[rr] += __shfl_xor(acc[rr], off, 64);
        }

        // elementwise gate update: lanes 0,1 of each wave (jj = L)
        if (L < 2) {
            float gi = acc[0 + L] + pxv[0];
            float gf = acc[2 + L] + pxv[1];
            float gg = acc[4 + L] + pxv[2];
            float go = acc[6 + L] + pxv[3];
            float iv = fast_sig(gi);
            float fv = fast_sig(gf);
            float gv = fast_tanh(gg);
            float ov = fast_sig(go);
            c0 = fv * c0 + iv * gv;
            float h = ov * fast_tanh(c0);
            int j = w * 8 + 2 * wave + L;
            // publish tagged h FIRST (critical path), then the log
            uint32_t word = bf16_bits(h) | ((uint32_t)(t + 1) << 16);
            __hip_atomic_store(dstb + j, word, __ATOMIC_RELAXED, __HIP_MEMORY_SCOPE_AGENT);
            lstm_out[(size_t)t * 1024 + j] = h;
        }
    }
}

// ---------- log-softmax over axis 0 (columns of [8192][512]) ----------
__global__ void sm_partial(const float* __restrict__ logits, float* __restrict__ pM,
                           float* __restrict__ pS) {
    const int cb = blockIdx.x, rb = blockIdx.y, tid = threadIdx.x;
    const int c = cb * 64 + (tid & 63);
    const int r0 = rb * 256 + (tid >> 6) * 64;
    const float* p = logits + (size_t)r0 * 512 + c;
    float m = -1e30f;
    for (int k = 0; k < 64; ++k) m = fmaxf(m, p[(size_t)k * 512]);
    float s = 0.f;
    for (int k = 0; k < 64; ++k) s += __expf(p[(size_t)k * 512] - m);
    __shared__ float sM[4][64], sS[4][64];
    sM[tid >> 6][tid & 63] = m;
    sS[tid >> 6][tid & 63] = s;
    __syncthreads();
    if (tid < 64) {
        float M = sM[0][tid];
        for (int i = 1; i < 4; ++i) M = fmaxf(M, sM[i][tid]);
        float S = 0.f;
        for (int i = 0; i < 4; ++i) S += sS[i][tid] * __expf(sM[i][tid] - M);
        pM[rb * 512 + cb * 64 + tid] = M;
        pS[rb * 512 + cb * 64 + tid] = S;
    }
}

__global__ void sm_combine(const float* __restrict__ pM, const float* __restrict__ pS,
                           float* __restrict__ cc) {
    const int c = threadIdx.x;   // 512 threads
    float M = -1e30f;
    for (int i = 0; i < 32; ++i) M = fmaxf(M, pM[i * 512 + c]);
    float S = 0.f;
    for (int i = 0; i < 32; ++i) S += pS[i * 512 + c] * __expf(pM[i * 512 + c] - M);
    cc[c] = M + logf(S);
}

__global__ void sm_apply(float* __restrict__ out, const float* __restrict__ cc) {
    const int idx = blockIdx.x * 256 + threadIdx.x;    // float4 index, exactly 1M
    float4 v = ((const float4*)out)[idx];
    float4 b = ((const float4*)cc)[idx & 127];
    v.x -= b.x; v.y -= b.y; v.z -= b.z; v.w -= b.w;
    ((float4*)out)[idx] = v;
}

// ---------- launch ----------
extern "C" void kernel_launch(void* const* d_in, const int* in_sizes, int n_in,
                              void* d_out, int out_size, void* d_ws, size_t ws_size,
                              hipStream_t stream) {
    (void)in_sizes; (void)n_in; (void)out_size; (void)ws_size;
    const float* x    = (const float*)d_in[0];
    const float* Wih  = (const float*)d_in[1];
    const float* Whh  = (const float*)d_in[2];
    const float* bih  = (const float*)d_in[3];
    const float* bhh  = (const float*)d_in[4];
    const float* Wout = (const float*)d_in[5];
    const float* bout = (const float*)d_in[6];
    float* out = (float*)d_out;

    char* ws = (char*)d_ws;
    uint32_t* pxp   = (uint32_t*)(ws + 0ull);            // 8192*2048 words   (67,108,864 B)
    uint32_t* wpk   = (uint32_t*)(ws + 67108864ull);     // 128*32*512 words  ( 8,388,608 B)
    float* lstm_out = (float*)   (ws + 75497472ull);     // 8192*1024 f32     (33,554,432 B)
    float* biasc    = (float*)   (ws + 109051904ull);    // 4096 f32 (16 KB)
    uint32_t* htag  = (uint32_t*)(ws + 109068288ull);    // 2*1024 words (8 KB)
    float* pM       = (float*)   (ws + 109076480ull);    // 32*512 f32 (64 KB)
    float* pS       = (float*)   (ws + 109142016ull);    // 32*512 f32 (64 KB)
    float* cc       = (float*)   (ws + 109207552ull);    // 512 f32

    // deterministic per-call state: H[0] = 0 with tag 0
    hipMemsetAsync(htag, 0, 8192, stream);

    prep_whh<<<8192, 256, 0, stream>>>(Whh, wpk);
    prep_bias<<<16, 256, 0, stream>>>(bih, bhh, biasc);

    // px = x @ W_ih^T + (b_ih + b_hh), stored packed bf16
    gemm_bt<true><<<dim3(64, 32), 256, 0, stream>>>(x, Wih, biasc, (void*)pxp, 4096, 1024);

    hipFuncSetAttribute(reinterpret_cast<const void*>(&lstm_rec),
                        hipFuncAttributeMaxDynamicSharedMemorySize, 65536);
    lstm_rec<<<NWG, 256, 65536, stream>>>(wpk, pxp, htag, lstm_out);

    // logits = lstm_out @ W_out^T + b_out  -> d_out
    gemm_bt<false><<<dim3(64, 4), 256, 0, stream>>>(lstm_out, Wout, bout, (void*)out, 512, 1024);

    // log-softmax over sequence axis (columns)
    sm_partial<<<dim3(8, 32), 256, 0, stream>>>(out, pM, pS);
    sm_combine<<<1, 512, 0, stream>>>(pM, pS, cc);
    sm_apply<<<4096, 256, 0, stream>>>(out, cc);
}